// Round 1
// baseline (1159.389 us; speedup 1.0000x reference)
//
#include <hip/hip_runtime.h>
#include <math.h>

#define NN   50000
#define INF_ 256
#define HID  64
#define OUTF 32
#define EE   800000

// ---------------- degree / dinv ----------------
__global__ __launch_bounds__(256) void k_init_deg(float* __restrict__ deg) {
    int i = blockIdx.x * 256 + threadIdx.x;
    if (i < 3 * NN) deg[i] = 1.0f;   // self-loop weight
}

__global__ __launch_bounds__(256) void k_deg_accum(
        const int* __restrict__ ei1, const int* __restrict__ ei2, const int* __restrict__ ei3,
        const float* __restrict__ ew1, const float* __restrict__ ew2, const float* __restrict__ ew3,
        float* __restrict__ deg) {
    int b = blockIdx.y;
    const int*   ei = (b == 0) ? ei1 : (b == 1) ? ei2 : ei3;
    const float* ew = (b == 0) ? ew1 : (b == 1) ? ew2 : ew3;
    int e = blockIdx.x * 256 + threadIdx.x;      // E = 800000 = 3125*256 exact
    atomicAdd(&deg[b * NN + ei[EE + e]], ew[e]);
}

__global__ __launch_bounds__(256) void k_rsqrt(float* __restrict__ deg) {
    int i = blockIdx.x * 256 + threadIdx.x;
    if (i < 3 * NN) deg[i] = rsqrtf(deg[i]);
}

// ---------------- layer-1 GEMM: h = x@W ; e_init = b + dinv^2*h ----------------
// block 256 = 4 waves; each wave: 64 cols x 4 rows. blockIdx.y = branch.
__global__ __launch_bounds__(256) void k_gemm1(
        const float* __restrict__ x1, const float* __restrict__ x2, const float* __restrict__ x3,
        const float* __restrict__ W1, const float* __restrict__ W2, const float* __restrict__ W3,
        const float* __restrict__ b1, const float* __restrict__ b2, const float* __restrict__ b3,
        const float* __restrict__ dinv,
        float* __restrict__ h, float* __restrict__ e) {
    __shared__ float Wt[HID][INF_ + 4];   // transposed W, padded: even bank use on b128 reads
    int b = blockIdx.y;
    const float* x  = (b == 0) ? x1 : (b == 1) ? x2 : x3;
    const float* W  = (b == 0) ? W1 : (b == 1) ? W2 : W3;
    const float* bi = (b == 0) ? b1 : (b == 1) ? b2 : b3;
    const float* dv = dinv + b * NN;
    float* hb = h + (size_t)b * NN * HID;
    float* eb = e + (size_t)b * NN * HID;

    int t = threadIdx.x;
    for (int idx = t; idx < INF_ * HID; idx += 256) {
        int k = idx >> 6, col = idx & 63;
        Wt[col][k] = W[idx];
    }
    __syncthreads();

    int col  = t & 63;
    int wid  = __builtin_amdgcn_readfirstlane(t >> 6);          // wave-uniform
    int row0 = blockIdx.x * 16 + wid * 4;                       // 50000 = 3125*16 exact

    float acc[4] = {0.f, 0.f, 0.f, 0.f};
    const float4* x4 = reinterpret_cast<const float4*>(x);
    for (int k4 = 0; k4 < INF_ / 4; ++k4) {
        float4 wv = *reinterpret_cast<const float4*>(&Wt[col][k4 * 4]);
#pragma unroll
        for (int r = 0; r < 4; ++r) {
            float4 xv = x4[(size_t)(row0 + r) * (INF_ / 4) + k4];   // wave-uniform -> s_load
            acc[r] += xv.x * wv.x + xv.y * wv.y + xv.z * wv.z + xv.w * wv.w;
        }
    }
    float bc = bi[col];
#pragma unroll
    for (int r = 0; r < 4; ++r) {
        int row = row0 + r;
        float d = dv[row];
        hb[(size_t)row * HID + col] = acc[r];
        eb[(size_t)row * HID + col] = bc + d * d * acc[r];   // bias + self-loop term
    }
}

// ---------------- layer-1 edge aggregation (atomic scatter) ----------------
// 4 edges per block, 64 feature lanes per edge. blockIdx.y = branch.
__global__ __launch_bounds__(256) void k_eagg1(
        const int* __restrict__ ei1, const int* __restrict__ ei2, const int* __restrict__ ei3,
        const float* __restrict__ ew1, const float* __restrict__ ew2, const float* __restrict__ ew3,
        const float* __restrict__ dinv,
        const float* __restrict__ h, float* __restrict__ e) {
    int b = blockIdx.y;
    const int*   ei = (b == 0) ? ei1 : (b == 1) ? ei2 : ei3;
    const float* ew = (b == 0) ? ew1 : (b == 1) ? ew2 : ew3;
    const float* dv = dinv + b * NN;
    const float* hb = h + (size_t)b * NN * HID;
    float*       eb = e + (size_t)b * NN * HID;

    int f   = threadIdx.x & 63;
    int sub = __builtin_amdgcn_readfirstlane(threadIdx.x >> 6);
    int eid = blockIdx.x * 4 + sub;                 // E = 200000*4 exact
    int src = ei[eid];
    int dst = ei[EE + eid];
    float norm = dv[src] * ew[eid] * dv[dst];
    atomicAdd(&eb[(size_t)dst * HID + f], norm * hb[(size_t)src * HID + f]);
}

// ---------------- attention + combine ----------------
// 1 wave per node (64 feature lanes). 4 nodes/block.
__global__ __launch_bounds__(256) void k_attn(
        const float* __restrict__ e, const float* __restrict__ fc_w, const float* __restrict__ fc_b,
        float* __restrict__ combined, float* __restrict__ coef_out) {
    int f   = threadIdx.x & 63;
    int sub = __builtin_amdgcn_readfirstlane(threadIdx.x >> 6);
    int n   = blockIdx.x * 4 + sub;                 // 50000 = 12500*4 exact
    float wv = fc_w[f];
    float fb = fc_b[0];
    float ev[3], c[3];
#pragma unroll
    for (int b = 0; b < 3; ++b) {
        float t = e[(size_t)b * NN * HID + (size_t)n * HID + f];
        ev[b] = fmaxf(t, 0.f);                      // ReLU
        float d = ev[b] * wv;
#pragma unroll
        for (int off = 32; off > 0; off >>= 1) d += __shfl_xor(d, off);
        float z = d + fb;
        z = (z > 0.f) ? z : 0.01f * z;              // leaky_relu
        c[b] = expf(z);
    }
    float cd = c[0] + c[1] + c[2];
    float coef0 = c[0] / cd, coef1 = c[1] / cd, coef2 = c[2] / cd;
    combined[(size_t)n * HID + f] = ev[0] * coef0 + ev[1] * coef1 + ev[2] * coef2;
    if (f == 0) {
        coef_out[n]          = coef0;
        coef_out[NN + n]     = coef1;
        coef_out[2 * NN + n] = coef2;
    }
}

// ---------------- layer-2 GEMM (all 3 branches) + out init ----------------
// block 256: 8 rows x 32 cols.
__global__ __launch_bounds__(256) void k_gemm2(
        const float* __restrict__ combined,
        const float* __restrict__ W11, const float* __restrict__ W22, const float* __restrict__ W33,
        const float* __restrict__ b11, const float* __restrict__ b22, const float* __restrict__ b33,
        const float* __restrict__ dinv,
        float* __restrict__ h2, float* __restrict__ out) {
    __shared__ float Ws[3][HID][OUTF];   // 24 KB
    int t = threadIdx.x;
    for (int idx = t; idx < HID * OUTF; idx += 256) {
        Ws[0][idx >> 5][idx & 31] = W11[idx];
        Ws[1][idx >> 5][idx & 31] = W22[idx];
        Ws[2][idx >> 5][idx & 31] = W33[idx];
    }
    __syncthreads();

    int col = t & 31;
    int sub = t >> 5;
    int row = blockIdx.x * 8 + sub;                 // 50000 = 6250*8 exact
    float acc0 = 0.f, acc1 = 0.f, acc2 = 0.f;
    for (int k = 0; k < HID; ++k) {
        float cv = combined[(size_t)row * HID + k];
        acc0 += cv * Ws[0][k][col];
        acc1 += cv * Ws[1][k][col];
        acc2 += cv * Ws[2][k][col];
    }
    float d0 = dinv[row], d1 = dinv[NN + row], d2 = dinv[2 * NN + row];
    h2[(size_t)0 * NN * OUTF + (size_t)row * OUTF + col] = acc0;
    h2[(size_t)1 * NN * OUTF + (size_t)row * OUTF + col] = acc1;
    h2[(size_t)2 * NN * OUTF + (size_t)row * OUTF + col] = acc2;
    out[(size_t)row * OUTF + col] =
        b11[col] + b22[col] + b33[col] + d0 * d0 * acc0 + d1 * d1 * acc1 + d2 * d2 * acc2;
}

// ---------------- layer-2 edge aggregation ----------------
// 8 edges per block, 32 feature lanes per edge. blockIdx.y = branch.
__global__ __launch_bounds__(256) void k_eagg2(
        const int* __restrict__ ei1, const int* __restrict__ ei2, const int* __restrict__ ei3,
        const float* __restrict__ ew1, const float* __restrict__ ew2, const float* __restrict__ ew3,
        const float* __restrict__ dinv,
        const float* __restrict__ h2, float* __restrict__ out) {
    int b = blockIdx.y;
    const int*   ei = (b == 0) ? ei1 : (b == 1) ? ei2 : ei3;
    const float* ew = (b == 0) ? ew1 : (b == 1) ? ew2 : ew3;
    const float* dv = dinv + b * NN;
    const float* hb = h2 + (size_t)b * NN * OUTF;

    int f   = threadIdx.x & 31;
    int sub = threadIdx.x >> 5;
    int eid = blockIdx.x * 8 + sub;                 // E = 100000*8 exact
    int src = ei[eid];
    int dst = ei[EE + eid];
    float norm = dv[src] * ew[eid] * dv[dst];
    atomicAdd(&out[(size_t)dst * OUTF + f], norm * hb[(size_t)src * OUTF + f]);
}

// ---------------- launch ----------------
extern "C" void kernel_launch(void* const* d_in, const int* in_sizes, int n_in,
                              void* d_out, int out_size, void* d_ws, size_t ws_size,
                              hipStream_t stream) {
    const float* x1  = (const float*)d_in[0];
    const float* x2  = (const float*)d_in[1];
    const float* x3  = (const float*)d_in[2];
    const int*   ei1 = (const int*)d_in[3];
    const int*   ei2 = (const int*)d_in[4];
    const int*   ei3 = (const int*)d_in[5];
    const float* ew1 = (const float*)d_in[6];
    const float* ew2 = (const float*)d_in[7];
    const float* ew3 = (const float*)d_in[8];
    const float* W1  = (const float*)d_in[9];
    const float* W2  = (const float*)d_in[10];
    const float* W3  = (const float*)d_in[11];
    const float* b1  = (const float*)d_in[12];
    const float* b2  = (const float*)d_in[13];
    const float* b3  = (const float*)d_in[14];
    const float* fcw = (const float*)d_in[15];
    const float* fcb = (const float*)d_in[16];
    const float* W11 = (const float*)d_in[17];
    const float* W22 = (const float*)d_in[18];
    const float* W33 = (const float*)d_in[19];
    const float* b11 = (const float*)d_in[20];
    const float* b22 = (const float*)d_in[21];
    const float* b33 = (const float*)d_in[22];

    float* out = (float*)d_out;                       // [N*32] sum, then 3x [N] coefs
    float* coef_out = out + (size_t)NN * OUTF;

    float* ws   = (float*)d_ws;
    float* dinv = ws;                                 // 3*N
    float* h    = dinv + 3 * NN;                      // 3*N*64  (reused as h2 later)
    float* e    = h + (size_t)3 * NN * HID;           // 3*N*64
    float* comb = e + (size_t)3 * NN * HID;           // N*64
    float* h2   = h;                                  // alias: h dead after attention

    k_init_deg<<<dim3((3 * NN + 255) / 256), 256, 0, stream>>>(dinv);
    k_deg_accum<<<dim3(EE / 256, 3), 256, 0, stream>>>(ei1, ei2, ei3, ew1, ew2, ew3, dinv);
    k_rsqrt<<<dim3((3 * NN + 255) / 256), 256, 0, stream>>>(dinv);

    k_gemm1<<<dim3(NN / 16, 3), 256, 0, stream>>>(x1, x2, x3, W1, W2, W3, b1, b2, b3,
                                                  dinv, h, e);
    k_eagg1<<<dim3(EE / 4, 3), 256, 0, stream>>>(ei1, ei2, ei3, ew1, ew2, ew3, dinv, h, e);

    k_attn<<<dim3(NN / 4), 256, 0, stream>>>(e, fcw, fcb, comb, coef_out);

    k_gemm2<<<dim3(NN / 8), 256, 0, stream>>>(comb, W11, W22, W33, b11, b22, b33,
                                              dinv, h2, out);
    k_eagg2<<<dim3(EE / 8, 3), 256, 0, stream>>>(ei1, ei2, ei3, ew1, ew2, ew3, dinv, h2, out);
}

// Round 2
// 891.915 us; speedup vs baseline: 1.2999x; 1.2999x over previous
//
#include <hip/hip_runtime.h>
#include <math.h>

#define NN   50000
#define INF_ 256
#define HID  64
#define OUTF 32
#define EE   800000
#define TOTN (3 * NN)

// ---------------- init: deg=1 (self-loop), cnt=0, total=0 ----------------
__global__ __launch_bounds__(256) void k_init(float* __restrict__ deg,
                                              int* __restrict__ cnt,
                                              int* __restrict__ total) {
    int i = blockIdx.x * 256 + threadIdx.x;
    if (i < TOTN) { deg[i] = 1.0f; cnt[i] = 0; }
    if (i == 0) *total = 0;
}

// ---------------- histogram: per-dst degree (weighted) + edge count ----------------
__global__ __launch_bounds__(256) void k_hist(
        const int* __restrict__ ei1, const int* __restrict__ ei2, const int* __restrict__ ei3,
        const float* __restrict__ ew1, const float* __restrict__ ew2, const float* __restrict__ ew3,
        float* __restrict__ deg, int* __restrict__ cnt) {
    int b = blockIdx.y;
    const int*   ei = (b == 0) ? ei1 : (b == 1) ? ei2 : ei3;
    const float* ew = (b == 0) ? ew1 : (b == 1) ? ew2 : ew3;
    int e = blockIdx.x * 256 + threadIdx.x;          // EE = 3125*256 exact
    int dst = ei[EE + e];
    atomicAdd(&deg[b * NN + dst], ew[e]);
    atomicAdd(&cnt[b * NN + dst], 1);
}

__global__ __launch_bounds__(256) void k_rsqrt(float* __restrict__ deg) {
    int i = blockIdx.x * 256 + threadIdx.x;
    if (i < TOTN) deg[i] = rsqrtf(deg[i]);
}

// ---------------- offsets: block-local scan + atomic block base ----------------
// Global ordering of blocks is irrelevant: only per-node contiguity matters.
__global__ __launch_bounds__(256) void k_offsets(const int* __restrict__ cnt,
                                                 int* __restrict__ cur,
                                                 int* __restrict__ total) {
    __shared__ int s[256];
    __shared__ int s_base;
    int t = threadIdx.x;
    int base_i = blockIdx.x * 1024 + t * 4;
    int c[4]; int sum = 0;
#pragma unroll
    for (int k = 0; k < 4; ++k) {
        int i = base_i + k;
        c[k] = (i < TOTN) ? cnt[i] : 0;
        sum += c[k];
    }
    s[t] = sum;
    __syncthreads();
    for (int d = 1; d < 256; d <<= 1) {
        int v = (t >= d) ? s[t - d] : 0;
        __syncthreads();
        s[t] += v;
        __syncthreads();
    }
    if (t == 255) s_base = atomicAdd(total, s[255]);
    __syncthreads();
    int run = s_base + s[t] - sum;   // exclusive offset for this thread's first elem
#pragma unroll
    for (int k = 0; k < 4; ++k) {
        int i = base_i + k;
        if (i < TOTN) cur[i] = run;
        run += c[k];
    }
}

// ---------------- fill CSR: csr_src + precomputed norm ----------------
__global__ __launch_bounds__(256) void k_fill(
        const int* __restrict__ ei1, const int* __restrict__ ei2, const int* __restrict__ ei3,
        const float* __restrict__ ew1, const float* __restrict__ ew2, const float* __restrict__ ew3,
        const float* __restrict__ dinv, int* __restrict__ cur,
        int* __restrict__ csr_src, float* __restrict__ csr_w) {
    int b = blockIdx.y;
    const int*   ei = (b == 0) ? ei1 : (b == 1) ? ei2 : ei3;
    const float* ew = (b == 0) ? ew1 : (b == 1) ? ew2 : ew3;
    int e = blockIdx.x * 256 + threadIdx.x;
    int src = ei[e];
    int dst = ei[EE + e];
    float norm = dinv[b * NN + src] * ew[e] * dinv[b * NN + dst];
    int pos = atomicAdd(&cur[b * NN + dst], 1);      // cur ends at start+cnt
    csr_src[pos] = src;
    csr_w[pos]  = norm;
}

// ---------------- layer-1 GEMM: h = x@W ----------------
__global__ __launch_bounds__(256) void k_gemm1(
        const float* __restrict__ x1, const float* __restrict__ x2, const float* __restrict__ x3,
        const float* __restrict__ W1, const float* __restrict__ W2, const float* __restrict__ W3,
        float* __restrict__ h) {
    __shared__ float Wt[HID][INF_ + 4];
    int b = blockIdx.y;
    const float* x = (b == 0) ? x1 : (b == 1) ? x2 : x3;
    const float* W = (b == 0) ? W1 : (b == 1) ? W2 : W3;
    float* hb = h + (size_t)b * NN * HID;

    int t = threadIdx.x;
    for (int idx = t; idx < INF_ * HID; idx += 256) {
        Wt[idx & 63][idx >> 6] = W[idx];
    }
    __syncthreads();

    int col  = t & 63;
    int wid  = __builtin_amdgcn_readfirstlane(t >> 6);
    int row0 = blockIdx.x * 16 + wid * 4;            // 50000 = 3125*16 exact

    float acc[4] = {0.f, 0.f, 0.f, 0.f};
    const float4* x4 = reinterpret_cast<const float4*>(x);
    for (int k4 = 0; k4 < INF_ / 4; ++k4) {
        float4 wv = *reinterpret_cast<const float4*>(&Wt[col][k4 * 4]);
#pragma unroll
        for (int r = 0; r < 4; ++r) {
            float4 xv = x4[(size_t)(row0 + r) * (INF_ / 4) + k4];
            acc[r] += xv.x * wv.x + xv.y * wv.y + xv.z * wv.z + xv.w * wv.w;
        }
    }
#pragma unroll
    for (int r = 0; r < 4; ++r)
        hb[(size_t)(row0 + r) * HID + col] = acc[r];
}

// ---------------- layer-1 aggregation: CSR gather, register accumulate ----------------
// One wave per node (64 feature lanes), 4 nodes/block. Bias + self-loop folded in.
__global__ __launch_bounds__(256) void k_agg1(
        const int* __restrict__ csr_src, const float* __restrict__ csr_w,
        const int* __restrict__ cur, const int* __restrict__ cnt,
        const float* __restrict__ dinv,
        const float* __restrict__ b1, const float* __restrict__ b2, const float* __restrict__ b3,
        const float* __restrict__ h, float* __restrict__ e) {
    int b = blockIdx.y;
    const float* bi = (b == 0) ? b1 : (b == 1) ? b2 : b3;
    const float* hb = h + (size_t)b * NN * HID;
    float*       eb = e + (size_t)b * NN * HID;

    int f   = threadIdx.x & 63;
    int sub = __builtin_amdgcn_readfirstlane(threadIdx.x >> 6);
    int n   = blockIdx.x * 4 + sub;                  // 50000 = 12500*4 exact
    int i   = b * NN + n;
    int c   = cnt[i];
    int st  = cur[i] - c;                            // cur holds end after fill
    float d = dinv[i];
    float acc = bi[f] + d * d * hb[(size_t)n * HID + f];

    int j = 0;
    for (; j + 2 <= c; j += 2) {
        int   s0 = csr_src[st + j],   s1 = csr_src[st + j + 1];
        float w0 = csr_w[st + j],     w1 = csr_w[st + j + 1];
        float v0 = hb[(size_t)s0 * HID + f];
        float v1 = hb[(size_t)s1 * HID + f];
        acc = fmaf(w0, v0, acc);
        acc = fmaf(w1, v1, acc);
    }
    if (j < c) {
        int   s0 = csr_src[st + j];
        float w0 = csr_w[st + j];
        acc = fmaf(w0, hb[(size_t)s0 * HID + f], acc);
    }
    eb[(size_t)n * HID + f] = acc;
}

// ---------------- attention + combine (combined aliases e branch 0) ----------------
__global__ __launch_bounds__(256) void k_attn(
        const float* __restrict__ e, const float* __restrict__ fc_w, const float* __restrict__ fc_b,
        float* __restrict__ combined, float* __restrict__ coef_out) {
    int f   = threadIdx.x & 63;
    int sub = __builtin_amdgcn_readfirstlane(threadIdx.x >> 6);
    int n   = blockIdx.x * 4 + sub;
    float wv = fc_w[f];
    float fb = fc_b[0];
    float ev[3], c[3];
#pragma unroll
    for (int b = 0; b < 3; ++b) {
        float t = e[(size_t)b * NN * HID + (size_t)n * HID + f];
        ev[b] = fmaxf(t, 0.f);
        float d = ev[b] * wv;
#pragma unroll
        for (int off = 32; off > 0; off >>= 1) d += __shfl_xor(d, off);
        float z = d + fb;
        z = (z > 0.f) ? z : 0.01f * z;
        c[b] = expf(z);
    }
    float cd = c[0] + c[1] + c[2];
    float coef0 = c[0] / cd, coef1 = c[1] / cd, coef2 = c[2] / cd;
    combined[(size_t)n * HID + f] = ev[0] * coef0 + ev[1] * coef1 + ev[2] * coef2;
    if (f == 0) {
        coef_out[n]          = coef0;
        coef_out[NN + n]     = coef1;
        coef_out[2 * NN + n] = coef2;
    }
}

// ---------------- layer-2 GEMM: h2[b] = combined @ W_b ----------------
__global__ __launch_bounds__(256) void k_gemm2(
        const float* __restrict__ combined,
        const float* __restrict__ W11, const float* __restrict__ W22, const float* __restrict__ W33,
        float* __restrict__ h2) {
    __shared__ float Ws[3][HID][OUTF];
    int t = threadIdx.x;
    for (int idx = t; idx < HID * OUTF; idx += 256) {
        Ws[0][idx >> 5][idx & 31] = W11[idx];
        Ws[1][idx >> 5][idx & 31] = W22[idx];
        Ws[2][idx >> 5][idx & 31] = W33[idx];
    }
    __syncthreads();

    int col = t & 31;
    int sub = t >> 5;
    int row = blockIdx.x * 8 + sub;                  // 50000 = 6250*8 exact
    float acc0 = 0.f, acc1 = 0.f, acc2 = 0.f;
    for (int k = 0; k < HID; ++k) {
        float cv = combined[(size_t)row * HID + k];
        acc0 += cv * Ws[0][k][col];
        acc1 += cv * Ws[1][k][col];
        acc2 += cv * Ws[2][k][col];
    }
    h2[(size_t)0 * NN * OUTF + (size_t)row * OUTF + col] = acc0;
    h2[(size_t)1 * NN * OUTF + (size_t)row * OUTF + col] = acc1;
    h2[(size_t)2 * NN * OUTF + (size_t)row * OUTF + col] = acc2;
}

// ---------------- layer-2 aggregation: one wave per node, all 3 branches ----------------
// Lanes: f = lane&31, half = lane>>5 takes alternating edges; shfl_xor(32) reduce.
__global__ __launch_bounds__(256) void k_agg2(
        const int* __restrict__ csr_src, const float* __restrict__ csr_w,
        const int* __restrict__ cur, const int* __restrict__ cnt,
        const float* __restrict__ dinv,
        const float* __restrict__ b11, const float* __restrict__ b22, const float* __restrict__ b33,
        const float* __restrict__ h2, float* __restrict__ out) {
    int f    = threadIdx.x & 31;
    int half = (threadIdx.x >> 5) & 1;
    int sub  = __builtin_amdgcn_readfirstlane(threadIdx.x >> 6);
    int n    = blockIdx.x * 4 + sub;

    float tot = b11[f] + b22[f] + b33[f];
#pragma unroll
    for (int b = 0; b < 3; ++b) {
        int i  = b * NN + n;
        int c  = cnt[i];
        int st = cur[i] - c;
        const float* h2b = h2 + (size_t)b * NN * OUTF;
        float accb = 0.f;
        for (int j = half; j < c; j += 2) {
            int   s = csr_src[st + j];
            float w = csr_w[st + j];
            accb = fmaf(w, h2b[(size_t)s * OUTF + f], accb);
        }
        accb += __shfl_xor(accb, 32);
        float d = dinv[i];
        tot += accb + d * d * h2b[(size_t)n * OUTF + f];
    }
    if (half == 0) out[(size_t)n * OUTF + f] = tot;
}

// ---------------- launch ----------------
extern "C" void kernel_launch(void* const* d_in, const int* in_sizes, int n_in,
                              void* d_out, int out_size, void* d_ws, size_t ws_size,
                              hipStream_t stream) {
    const float* x1  = (const float*)d_in[0];
    const float* x2  = (const float*)d_in[1];
    const float* x3  = (const float*)d_in[2];
    const int*   ei1 = (const int*)d_in[3];
    const int*   ei2 = (const int*)d_in[4];
    const int*   ei3 = (const int*)d_in[5];
    const float* ew1 = (const float*)d_in[6];
    const float* ew2 = (const float*)d_in[7];
    const float* ew3 = (const float*)d_in[8];
    const float* W1  = (const float*)d_in[9];
    const float* W2  = (const float*)d_in[10];
    const float* W3  = (const float*)d_in[11];
    const float* b1  = (const float*)d_in[12];
    const float* b2  = (const float*)d_in[13];
    const float* b3  = (const float*)d_in[14];
    const float* fcw = (const float*)d_in[15];
    const float* fcb = (const float*)d_in[16];
    const float* W11 = (const float*)d_in[17];
    const float* W22 = (const float*)d_in[18];
    const float* W33 = (const float*)d_in[19];
    const float* b11 = (const float*)d_in[20];
    const float* b22 = (const float*)d_in[21];
    const float* b33 = (const float*)d_in[22];

    float* out = (float*)d_out;
    float* coef_out = out + (size_t)NN * OUTF;

    // workspace layout (floats/ints, 4B each)
    float* ws      = (float*)d_ws;
    float* dinv    = ws;                                   // 3N
    int*   cnt     = (int*)(dinv + TOTN);                  // 3N
    int*   cur     = cnt + TOTN;                           // 3N
    int*   total   = cur + TOTN;                           // 64 (pad)
    int*   csr_src = total + 64;                           // 3E
    float* csr_w   = (float*)(csr_src + 3 * EE);           // 3E
    float* h       = csr_w + 3 * EE;                       // 3N*64
    float* e       = h + (size_t)TOTN * HID;               // 3N*64
    float* comb    = e;                                    // alias: branch-0 of e (safe, see k_attn)
    float* h2      = h;                                    // alias: h dead after agg1

    k_init<<<dim3((TOTN + 255) / 256), 256, 0, stream>>>(dinv, cnt, total);
    k_hist<<<dim3(EE / 256, 3), 256, 0, stream>>>(ei1, ei2, ei3, ew1, ew2, ew3, dinv, cnt);
    k_rsqrt<<<dim3((TOTN + 255) / 256), 256, 0, stream>>>(dinv);
    k_offsets<<<dim3((TOTN + 1023) / 1024), 256, 0, stream>>>(cnt, cur, total);
    k_fill<<<dim3(EE / 256, 3), 256, 0, stream>>>(ei1, ei2, ei3, ew1, ew2, ew3,
                                                  dinv, cur, csr_src, csr_w);

    k_gemm1<<<dim3(NN / 16, 3), 256, 0, stream>>>(x1, x2, x3, W1, W2, W3, h);
    k_agg1<<<dim3(NN / 4, 3), 256, 0, stream>>>(csr_src, csr_w, cur, cnt, dinv,
                                                b1, b2, b3, h, e);
    k_attn<<<dim3(NN / 4), 256, 0, stream>>>(e, fcw, fcb, comb, coef_out);
    k_gemm2<<<dim3(NN / 8), 256, 0, stream>>>(comb, W11, W22, W33, h2);
    k_agg2<<<dim3(NN / 4), 256, 0, stream>>>(csr_src, csr_w, cur, cnt, dinv,
                                             b11, b22, b33, h2, out);
}

// Round 3
// 746.447 us; speedup vs baseline: 1.5532x; 1.1949x over previous
//
#include <hip/hip_runtime.h>
#include <math.h>

#define NN   50000
#define INF_ 256
#define HID  64
#define OUTF 32
#define EE   800000
#define TOTN (3 * NN)
#define BM   64
#define BK   64

// ---------------- init: deg=1 (self-loop), cnt=0, total=0 ----------------
__global__ __launch_bounds__(256) void k_init(float* __restrict__ deg,
                                              int* __restrict__ cnt,
                                              int* __restrict__ total) {
    int i = blockIdx.x * 256 + threadIdx.x;
    if (i < TOTN) { deg[i] = 1.0f; cnt[i] = 0; }
    if (i == 0) *total = 0;
}

// ---------------- histogram: per-dst degree (weighted) + edge count ----------------
__global__ __launch_bounds__(256) void k_hist(
        const int* __restrict__ ei1, const int* __restrict__ ei2, const int* __restrict__ ei3,
        const float* __restrict__ ew1, const float* __restrict__ ew2, const float* __restrict__ ew3,
        float* __restrict__ deg, int* __restrict__ cnt) {
    int b = blockIdx.y;
    const int*   ei = (b == 0) ? ei1 : (b == 1) ? ei2 : ei3;
    const float* ew = (b == 0) ? ew1 : (b == 1) ? ew2 : ew3;
    int e = blockIdx.x * 256 + threadIdx.x;          // EE = 3125*256 exact
    int dst = ei[EE + e];
    atomicAdd(&deg[b * NN + dst], ew[e]);
    atomicAdd(&cnt[b * NN + dst], 1);
}

__global__ __launch_bounds__(256) void k_rsqrt(float* __restrict__ deg) {
    int i = blockIdx.x * 256 + threadIdx.x;
    if (i < TOTN) deg[i] = rsqrtf(deg[i]);
}

// ---------------- offsets: block-local scan + atomic block base ----------------
__global__ __launch_bounds__(256) void k_offsets(const int* __restrict__ cnt,
                                                 int* __restrict__ cur,
                                                 int* __restrict__ total) {
    __shared__ int s[256];
    __shared__ int s_base;
    int t = threadIdx.x;
    int base_i = blockIdx.x * 1024 + t * 4;
    int c[4]; int sum = 0;
#pragma unroll
    for (int k = 0; k < 4; ++k) {
        int i = base_i + k;
        c[k] = (i < TOTN) ? cnt[i] : 0;
        sum += c[k];
    }
    s[t] = sum;
    __syncthreads();
    for (int d = 1; d < 256; d <<= 1) {
        int v = (t >= d) ? s[t - d] : 0;
        __syncthreads();
        s[t] += v;
        __syncthreads();
    }
    if (t == 255) s_base = atomicAdd(total, s[255]);
    __syncthreads();
    int run = s_base + s[t] - sum;
#pragma unroll
    for (int k = 0; k < 4; ++k) {
        int i = base_i + k;
        if (i < TOTN) cur[i] = run;
        run += c[k];
    }
}

// ---------------- fill CSR: csr_src + precomputed norm ----------------
__global__ __launch_bounds__(256) void k_fill(
        const int* __restrict__ ei1, const int* __restrict__ ei2, const int* __restrict__ ei3,
        const float* __restrict__ ew1, const float* __restrict__ ew2, const float* __restrict__ ew3,
        const float* __restrict__ dinv, int* __restrict__ cur,
        int* __restrict__ csr_src, float* __restrict__ csr_w) {
    int b = blockIdx.y;
    const int*   ei = (b == 0) ? ei1 : (b == 1) ? ei2 : ei3;
    const float* ew = (b == 0) ? ew1 : (b == 1) ? ew2 : ew3;
    int e = blockIdx.x * 256 + threadIdx.x;
    int src = ei[e];
    int dst = ei[EE + e];
    float norm = dinv[b * NN + src] * ew[e] * dinv[b * NN + dst];
    int pos = atomicAdd(&cur[b * NN + dst], 1);
    csr_src[pos] = src;
    csr_w[pos]  = norm;
}

// ---------------- layer-1 GEMM: h = x@W  (register-tiled fp32) ----------------
// BM=64 rows x 64 cols per block, BK=64, 256 threads, 4x4 micro-tile/thread.
__global__ __launch_bounds__(256) void k_gemm1(
        const float* __restrict__ x1, const float* __restrict__ x2, const float* __restrict__ x3,
        const float* __restrict__ W1, const float* __restrict__ W2, const float* __restrict__ W3,
        float* __restrict__ h) {
    __shared__ float xs[BM][BK + 4];   // +4 floats keeps float4 alignment; rows 2-way banked
    __shared__ float Ws[BK][HID];
    int b = blockIdx.y;
    const float* x = (b == 0) ? x1 : (b == 1) ? x2 : x3;
    const float* W = (b == 0) ? W1 : (b == 1) ? W2 : W3;
    float* hb = h + (size_t)b * NN * HID;

    int t  = threadIdx.x;
    int tx = t & 15;          // col0 = tx*4
    int ty = t >> 4;          // row0 = ty*4
    int row_base = blockIdx.x * BM;

    float acc[4][4] = {};
    const float4* x4base = reinterpret_cast<const float4*>(x);
    for (int kt = 0; kt < INF_ / BK; ++kt) {
#pragma unroll
        for (int j = 0; j < 4; ++j) {               // stage x tile: 1024 float4
            int flat = t + j * 256;
            int r = flat >> 4, c4 = flat & 15;
            int gr = row_base + r;
            float4 v = (gr < NN)
                ? x4base[(size_t)gr * (INF_ / 4) + kt * (BK / 4) + c4]
                : make_float4(0.f, 0.f, 0.f, 0.f);
            *reinterpret_cast<float4*>(&xs[r][c4 * 4]) = v;
        }
        const float4* W4 = reinterpret_cast<const float4*>(W) + kt * BK * (HID / 4);
#pragma unroll
        for (int j = 0; j < 4; ++j) {               // stage W tile: 1024 float4
            int flat = t + j * 256;
            int r = flat >> 4, c4 = flat & 15;
            *reinterpret_cast<float4*>(&Ws[r][c4 * 4]) = W4[flat];
        }
        __syncthreads();
#pragma unroll
        for (int k = 0; k < BK; ++k) {
            float4 wv = *reinterpret_cast<const float4*>(&Ws[k][tx * 4]);
            float xv[4];
#pragma unroll
            for (int i = 0; i < 4; ++i) xv[i] = xs[ty * 4 + i][k];
#pragma unroll
            for (int i = 0; i < 4; ++i) {
                acc[i][0] = fmaf(xv[i], wv.x, acc[i][0]);
                acc[i][1] = fmaf(xv[i], wv.y, acc[i][1]);
                acc[i][2] = fmaf(xv[i], wv.z, acc[i][2]);
                acc[i][3] = fmaf(xv[i], wv.w, acc[i][3]);
            }
        }
        __syncthreads();
    }
#pragma unroll
    for (int i = 0; i < 4; ++i) {
        int row = row_base + ty * 4 + i;
        if (row < NN)
            *reinterpret_cast<float4*>(&hb[(size_t)row * HID + tx * 4]) =
                make_float4(acc[i][0], acc[i][1], acc[i][2], acc[i][3]);
    }
}

// ---------------- layer-1 aggregation: CSR gather, register accumulate ----------------
// One wave per node (64 feature lanes), 4 nodes/block. Bias + self-loop + ReLU folded in.
__global__ __launch_bounds__(256) void k_agg1(
        const int* __restrict__ csr_src, const float* __restrict__ csr_w,
        const int* __restrict__ cur, const int* __restrict__ cnt,
        const float* __restrict__ dinv,
        const float* __restrict__ b1, const float* __restrict__ b2, const float* __restrict__ b3,
        const float* __restrict__ h, float* __restrict__ e) {
    int b = blockIdx.y;
    const float* bi = (b == 0) ? b1 : (b == 1) ? b2 : b3;
    const float* hb = h + (size_t)b * NN * HID;
    float*       eb = e + (size_t)b * NN * HID;

    int f   = threadIdx.x & 63;
    int sub = __builtin_amdgcn_readfirstlane(threadIdx.x >> 6);
    int n   = blockIdx.x * 4 + sub;
    int i   = b * NN + n;
    int c   = cnt[i];
    int st  = cur[i] - c;
    float d = dinv[i];
    float acc = bi[f] + d * d * hb[(size_t)n * HID + f];

    int j = 0;
    for (; j + 2 <= c; j += 2) {
        int   s0 = csr_src[st + j],   s1 = csr_src[st + j + 1];
        float w0 = csr_w[st + j],     w1 = csr_w[st + j + 1];
        float v0 = hb[(size_t)s0 * HID + f];
        float v1 = hb[(size_t)s1 * HID + f];
        acc = fmaf(w0, v0, acc);
        acc = fmaf(w1, v1, acc);
    }
    if (j < c) {
        int   s0 = csr_src[st + j];
        float w0 = csr_w[st + j];
        acc = fmaf(w0, hb[(size_t)s0 * HID + f], acc);
    }
    eb[(size_t)n * HID + f] = fmaxf(acc, 0.f);   // ReLU folded (e only consumed via ReLU)
}

// ---------------- attention + combine (e already ReLU'd) ----------------
__global__ __launch_bounds__(256) void k_attn(
        const float* __restrict__ e, const float* __restrict__ fc_w, const float* __restrict__ fc_b,
        float* __restrict__ combined, float* __restrict__ coef_out) {
    int f   = threadIdx.x & 63;
    int sub = __builtin_amdgcn_readfirstlane(threadIdx.x >> 6);
    int n   = blockIdx.x * 4 + sub;
    float wv = fc_w[f];
    float fb = fc_b[0];
    float ev[3], c[3];
#pragma unroll
    for (int b = 0; b < 3; ++b) {
        ev[b] = e[(size_t)b * NN * HID + (size_t)n * HID + f];
        float d = ev[b] * wv;
#pragma unroll
        for (int off = 32; off > 0; off >>= 1) d += __shfl_xor(d, off);
        float z = d + fb;
        z = (z > 0.f) ? z : 0.01f * z;
        c[b] = expf(z);
    }
    float cd = c[0] + c[1] + c[2];
    float coef0 = c[0] / cd, coef1 = c[1] / cd, coef2 = c[2] / cd;
    combined[(size_t)n * HID + f] = ev[0] * coef0 + ev[1] * coef1 + ev[2] * coef2;
    if (f == 0) {
        coef_out[n]          = coef0;
        coef_out[NN + n]     = coef1;
        coef_out[2 * NN + n] = coef2;
    }
}

// ---------------- layer-2 GEMM: h2[b] = combined @ W_b ----------------
__global__ __launch_bounds__(256) void k_gemm2(
        const float* __restrict__ combined,
        const float* __restrict__ W11, const float* __restrict__ W22, const float* __restrict__ W33,
        float* __restrict__ h2) {
    __shared__ float Ws[3][HID][OUTF];
    int t = threadIdx.x;
    for (int idx = t; idx < HID * OUTF; idx += 256) {
        Ws[0][idx >> 5][idx & 31] = W11[idx];
        Ws[1][idx >> 5][idx & 31] = W22[idx];
        Ws[2][idx >> 5][idx & 31] = W33[idx];
    }
    __syncthreads();

    int col = t & 31;
    int sub = t >> 5;
    int row = blockIdx.x * 8 + sub;
    float acc0 = 0.f, acc1 = 0.f, acc2 = 0.f;
    for (int k = 0; k < HID; ++k) {
        float cv = combined[(size_t)row * HID + k];
        acc0 += cv * Ws[0][k][col];
        acc1 += cv * Ws[1][k][col];
        acc2 += cv * Ws[2][k][col];
    }
    h2[(size_t)0 * NN * OUTF + (size_t)row * OUTF + col] = acc0;
    h2[(size_t)1 * NN * OUTF + (size_t)row * OUTF + col] = acc1;
    h2[(size_t)2 * NN * OUTF + (size_t)row * OUTF + col] = acc2;
}

// ---------------- layer-2 aggregation: one wave per node, all 3 branches ----------------
__global__ __launch_bounds__(256) void k_agg2(
        const int* __restrict__ csr_src, const float* __restrict__ csr_w,
        const int* __restrict__ cur, const int* __restrict__ cnt,
        const float* __restrict__ dinv,
        const float* __restrict__ b11, const float* __restrict__ b22, const float* __restrict__ b33,
        const float* __restrict__ h2, float* __restrict__ out) {
    int f    = threadIdx.x & 31;
    int half = (threadIdx.x >> 5) & 1;
    int sub  = __builtin_amdgcn_readfirstlane(threadIdx.x >> 6);
    int n    = blockIdx.x * 4 + sub;

    float tot = b11[f] + b22[f] + b33[f];
#pragma unroll
    for (int b = 0; b < 3; ++b) {
        int i  = b * NN + n;
        int c  = cnt[i];
        int st = cur[i] - c;
        const float* h2b = h2 + (size_t)b * NN * OUTF;
        float accb = 0.f;
        for (int j = half; j < c; j += 2) {
            int   s = csr_src[st + j];
            float w = csr_w[st + j];
            accb = fmaf(w, h2b[(size_t)s * OUTF + f], accb);
        }
        accb += __shfl_xor(accb, 32);
        float d = dinv[i];
        tot += accb + d * d * h2b[(size_t)n * OUTF + f];
    }
    if (half == 0) out[(size_t)n * OUTF + f] = tot;
}

// ---------------- launch ----------------
extern "C" void kernel_launch(void* const* d_in, const int* in_sizes, int n_in,
                              void* d_out, int out_size, void* d_ws, size_t ws_size,
                              hipStream_t stream) {
    const float* x1  = (const float*)d_in[0];
    const float* x2  = (const float*)d_in[1];
    const float* x3  = (const float*)d_in[2];
    const int*   ei1 = (const int*)d_in[3];
    const int*   ei2 = (const int*)d_in[4];
    const int*   ei3 = (const int*)d_in[5];
    const float* ew1 = (const float*)d_in[6];
    const float* ew2 = (const float*)d_in[7];
    const float* ew3 = (const float*)d_in[8];
    const float* W1  = (const float*)d_in[9];
    const float* W2  = (const float*)d_in[10];
    const float* W3  = (const float*)d_in[11];
    const float* b1  = (const float*)d_in[12];
    const float* b2  = (const float*)d_in[13];
    const float* b3  = (const float*)d_in[14];
    const float* fcw = (const float*)d_in[15];
    const float* fcb = (const float*)d_in[16];
    const float* W11 = (const float*)d_in[17];
    const float* W22 = (const float*)d_in[18];
    const float* W33 = (const float*)d_in[19];
    const float* b11 = (const float*)d_in[20];
    const float* b22 = (const float*)d_in[21];
    const float* b33 = (const float*)d_in[22];

    float* out = (float*)d_out;
    float* coef_out = out + (size_t)NN * OUTF;

    float* ws      = (float*)d_ws;
    float* dinv    = ws;                                   // 3N
    int*   cnt     = (int*)(dinv + TOTN);                  // 3N
    int*   cur     = cnt + TOTN;                           // 3N
    int*   total   = cur + TOTN;                           // 64 (pad)
    int*   csr_src = total + 64;                           // 3E
    float* csr_w   = (float*)(csr_src + 3 * EE);           // 3E
    float* h       = csr_w + 3 * EE;                       // 3N*64
    float* e       = h + (size_t)TOTN * HID;               // 3N*64
    float* comb    = e;                                    // alias branch-0 of e (k_attn in-place safe)
    float* h2      = h;                                    // alias: h dead after agg1

    k_init<<<dim3((TOTN + 255) / 256), 256, 0, stream>>>(dinv, cnt, total);
    k_hist<<<dim3(EE / 256, 3), 256, 0, stream>>>(ei1, ei2, ei3, ew1, ew2, ew3, dinv, cnt);
    k_rsqrt<<<dim3((TOTN + 255) / 256), 256, 0, stream>>>(dinv);
    k_offsets<<<dim3((TOTN + 1023) / 1024), 256, 0, stream>>>(cnt, cur, total);
    k_fill<<<dim3(EE / 256, 3), 256, 0, stream>>>(ei1, ei2, ei3, ew1, ew2, ew3,
                                                  dinv, cur, csr_src, csr_w);

    k_gemm1<<<dim3((NN + BM - 1) / BM, 3), 256, 0, stream>>>(x1, x2, x3, W1, W2, W3, h);
    k_agg1<<<dim3(NN / 4, 3), 256, 0, stream>>>(csr_src, csr_w, cur, cnt, dinv,
                                                b1, b2, b3, h, e);
    k_attn<<<dim3(NN / 4), 256, 0, stream>>>(e, fcw, fcb, comb, coef_out);
    k_gemm2<<<dim3(NN / 8), 256, 0, stream>>>(comb, W11, W22, W33, h2);
    k_agg2<<<dim3(NN / 4), 256, 0, stream>>>(csr_src, csr_w, cur, cnt, dinv,
                                             b11, b22, b33, h2, out);
}

// Round 4
// 555.769 us; speedup vs baseline: 2.0861x; 1.3431x over previous
//
#include <hip/hip_runtime.h>
#include <hip/hip_fp16.h>
#include <math.h>

#define NN   50000
#define INF_ 256
#define HID  64
#define OUTF 32
#define EE   800000
#define TOTN (3 * NN)
#define BM   64
#define BK   64

typedef unsigned long long u64;

// ---------------- init: packed hist = 0, total = 0 ----------------
__global__ __launch_bounds__(256) void k_init(u64* __restrict__ packed, int* __restrict__ total) {
    int i = blockIdx.x * 256 + threadIdx.x;
    if (i < TOTN) packed[i] = 0ULL;
    if (i == 0) *total = 0;
}

// ---------------- histogram: ONE 64-bit atomic per edge: (cnt<<40) | w*2^24 ----------------
__global__ __launch_bounds__(256) void k_hist(
        const int* __restrict__ ei1, const int* __restrict__ ei2, const int* __restrict__ ei3,
        const float* __restrict__ ew1, const float* __restrict__ ew2, const float* __restrict__ ew3,
        u64* __restrict__ packed) {
    int b = blockIdx.y;
    const int*   ei = (b == 0) ? ei1 : (b == 1) ? ei2 : ei3;
    const float* ew = (b == 0) ? ew1 : (b == 1) ? ew2 : ew3;
    int e = blockIdx.x * 256 + threadIdx.x;          // EE = 3125*256 exact
    int dst = ei[EE + e];
    u64 contrib = (1ULL << 40) | (u64)(unsigned int)(ew[e] * 16777216.0f);
    atomicAdd(&packed[b * NN + dst], contrib);
}

// ---------------- unpack: dinv = rsqrt(1 + sum_w), cnt ----------------
__global__ __launch_bounds__(256) void k_unpack(const u64* __restrict__ packed,
                                               float* __restrict__ dinv, int* __restrict__ cnt) {
    int i = blockIdx.x * 256 + threadIdx.x;
    if (i >= TOTN) return;
    u64 p = packed[i];
    cnt[i] = (int)(p >> 40);
    float deg = 1.0f + (float)(p & ((1ULL << 40) - 1)) * (1.0f / 16777216.0f);
    dinv[i] = rsqrtf(deg);
}

// ---------------- offsets: block-local scan + atomic block base ----------------
__global__ __launch_bounds__(256) void k_offsets(const int* __restrict__ cnt,
                                                 int* __restrict__ cur,
                                                 int* __restrict__ total) {
    __shared__ int s[256];
    __shared__ int s_base;
    int t = threadIdx.x;
    int base_i = blockIdx.x * 1024 + t * 4;
    int c[4]; int sum = 0;
#pragma unroll
    for (int k = 0; k < 4; ++k) {
        int i = base_i + k;
        c[k] = (i < TOTN) ? cnt[i] : 0;
        sum += c[k];
    }
    s[t] = sum;
    __syncthreads();
    for (int d = 1; d < 256; d <<= 1) {
        int v = (t >= d) ? s[t - d] : 0;
        __syncthreads();
        s[t] += v;
        __syncthreads();
    }
    if (t == 255) s_base = atomicAdd(total, s[255]);
    __syncthreads();
    int run = s_base + s[t] - sum;
#pragma unroll
    for (int k = 0; k < 4; ++k) {
        int i = base_i + k;
        if (i < TOTN) cur[i] = run;
        run += c[k];
    }
}

// ---------------- fill CSR: one packed 8B entry (norm<<32 | src) per edge ----------------
__global__ __launch_bounds__(256) void k_fill(
        const int* __restrict__ ei1, const int* __restrict__ ei2, const int* __restrict__ ei3,
        const float* __restrict__ ew1, const float* __restrict__ ew2, const float* __restrict__ ew3,
        const float* __restrict__ dinv, int* __restrict__ cur,
        u64* __restrict__ csr) {
    int b = blockIdx.y;
    const int*   ei = (b == 0) ? ei1 : (b == 1) ? ei2 : ei3;
    const float* ew = (b == 0) ? ew1 : (b == 1) ? ew2 : ew3;
    int e = blockIdx.x * 256 + threadIdx.x;
    int src = ei[e];
    int dst = ei[EE + e];
    float norm = dinv[b * NN + src] * ew[e] * dinv[b * NN + dst];
    int pos = atomicAdd(&cur[b * NN + dst], 1);      // cur ends at start+cnt
    csr[pos] = ((u64)__float_as_uint(norm) << 32) | (u64)(unsigned int)src;
}

// ---------------- layer-1 GEMM: h = x@W (fp16 out, register-tiled) ----------------
__global__ __launch_bounds__(256) void k_gemm1(
        const float* __restrict__ x1, const float* __restrict__ x2, const float* __restrict__ x3,
        const float* __restrict__ W1, const float* __restrict__ W2, const float* __restrict__ W3,
        __half* __restrict__ h) {
    __shared__ float xs[BM][BK + 4];
    __shared__ float Ws[BK][HID];
    int b = blockIdx.y;
    const float* x = (b == 0) ? x1 : (b == 1) ? x2 : x3;
    const float* W = (b == 0) ? W1 : (b == 1) ? W2 : W3;
    __half* hb = h + (size_t)b * NN * HID;

    int t  = threadIdx.x;
    int tx = t & 15;
    int ty = t >> 4;
    int row_base = blockIdx.x * BM;

    float acc[4][4] = {};
    const float4* x4base = reinterpret_cast<const float4*>(x);
    for (int kt = 0; kt < INF_ / BK; ++kt) {
#pragma unroll
        for (int j = 0; j < 4; ++j) {
            int flat = t + j * 256;
            int r = flat >> 4, c4 = flat & 15;
            int gr = row_base + r;
            float4 v = (gr < NN)
                ? x4base[(size_t)gr * (INF_ / 4) + kt * (BK / 4) + c4]
                : make_float4(0.f, 0.f, 0.f, 0.f);
            *reinterpret_cast<float4*>(&xs[r][c4 * 4]) = v;
        }
        const float4* W4 = reinterpret_cast<const float4*>(W) + kt * BK * (HID / 4);
#pragma unroll
        for (int j = 0; j < 4; ++j) {
            int flat = t + j * 256;
            int r = flat >> 4, c4 = flat & 15;
            *reinterpret_cast<float4*>(&Ws[r][c4 * 4]) = W4[flat];
        }
        __syncthreads();
#pragma unroll
        for (int k = 0; k < BK; ++k) {
            float4 wv = *reinterpret_cast<const float4*>(&Ws[k][tx * 4]);
            float xv[4];
#pragma unroll
            for (int i = 0; i < 4; ++i) xv[i] = xs[ty * 4 + i][k];
#pragma unroll
            for (int i = 0; i < 4; ++i) {
                acc[i][0] = fmaf(xv[i], wv.x, acc[i][0]);
                acc[i][1] = fmaf(xv[i], wv.y, acc[i][1]);
                acc[i][2] = fmaf(xv[i], wv.z, acc[i][2]);
                acc[i][3] = fmaf(xv[i], wv.w, acc[i][3]);
            }
        }
        __syncthreads();
    }
#pragma unroll
    for (int i = 0; i < 4; ++i) {
        int row = row_base + ty * 4 + i;
        if (row < NN) {
            ushort4 v;
            v.x = __half_as_ushort(__float2half(acc[i][0]));
            v.y = __half_as_ushort(__float2half(acc[i][1]));
            v.z = __half_as_ushort(__float2half(acc[i][2]));
            v.w = __half_as_ushort(__float2half(acc[i][3]));
            *reinterpret_cast<ushort4*>(&hb[(size_t)row * HID + tx * 4]) = v;
        }
    }
}

// ---------------- fused layer-1 aggregation (3 branches) + attention ----------------
// One wave per node: gather+bias+selfloop+ReLU for b=0..2, then softmax-attention.
__global__ __launch_bounds__(256) void k_agg_attn(
        const u64* __restrict__ csr, const int* __restrict__ cur, const int* __restrict__ cnt,
        const float* __restrict__ dinv,
        const float* __restrict__ b1, const float* __restrict__ b2, const float* __restrict__ b3,
        const __half* __restrict__ h,
        const float* __restrict__ fc_w, const float* __restrict__ fc_b,
        float* __restrict__ combined, float* __restrict__ coef_out) {
    int f   = threadIdx.x & 63;
    int sub = __builtin_amdgcn_readfirstlane(threadIdx.x >> 6);
    int n   = blockIdx.x * 4 + sub;                  // 50000 = 12500*4 exact
    float wv = fc_w[f];
    float fb = fc_b[0];

    float ev[3], c[3];
#pragma unroll
    for (int b = 0; b < 3; ++b) {
        const float* bi = (b == 0) ? b1 : (b == 1) ? b2 : b3;
        const __half* hb = h + (size_t)b * NN * HID;
        int i  = b * NN + n;
        int cc = cnt[i];
        int st = cur[i] - cc;
        float d = dinv[i];
        float acc = bi[f] + d * d * __half2float(hb[(size_t)n * HID + f]);

        int j = 0;
        for (; j + 2 <= cc; j += 2) {
            u64 e0 = csr[st + j], e1 = csr[st + j + 1];
            int   s0 = (int)(unsigned int)(e0 & 0xffffffffULL);
            int   s1 = (int)(unsigned int)(e1 & 0xffffffffULL);
            float w0 = __uint_as_float((unsigned int)(e0 >> 32));
            float w1 = __uint_as_float((unsigned int)(e1 >> 32));
            float v0 = __half2float(hb[(size_t)s0 * HID + f]);
            float v1 = __half2float(hb[(size_t)s1 * HID + f]);
            acc = fmaf(w0, v0, acc);
            acc = fmaf(w1, v1, acc);
        }
        if (j < cc) {
            u64 e0 = csr[st + j];
            int   s0 = (int)(unsigned int)(e0 & 0xffffffffULL);
            float w0 = __uint_as_float((unsigned int)(e0 >> 32));
            acc = fmaf(w0, __half2float(hb[(size_t)s0 * HID + f]), acc);
        }
        ev[b] = fmaxf(acc, 0.f);                     // ReLU

        float dd = ev[b] * wv;
#pragma unroll
        for (int off = 32; off > 0; off >>= 1) dd += __shfl_xor(dd, off);
        float z = dd + fb;
        z = (z > 0.f) ? z : 0.01f * z;
        c[b] = expf(z);
    }
    float cd = c[0] + c[1] + c[2];
    float coef0 = c[0] / cd, coef1 = c[1] / cd, coef2 = c[2] / cd;
    combined[(size_t)n * HID + f] = ev[0] * coef0 + ev[1] * coef1 + ev[2] * coef2;
    if (f == 0) {
        coef_out[n]          = coef0;
        coef_out[NN + n]     = coef1;
        coef_out[2 * NN + n] = coef2;
    }
}

// ---------------- layer-2 GEMM: h2[b] = combined @ W_b (fp16 out) ----------------
__global__ __launch_bounds__(256) void k_gemm2(
        const float* __restrict__ combined,
        const float* __restrict__ W11, const float* __restrict__ W22, const float* __restrict__ W33,
        __half* __restrict__ h2) {
    __shared__ float Ws[3][HID][OUTF];
    int t = threadIdx.x;
    for (int idx = t; idx < HID * OUTF; idx += 256) {
        Ws[0][idx >> 5][idx & 31] = W11[idx];
        Ws[1][idx >> 5][idx & 31] = W22[idx];
        Ws[2][idx >> 5][idx & 31] = W33[idx];
    }
    __syncthreads();

    int col = t & 31;
    int sub = t >> 5;
    int row = blockIdx.x * 8 + sub;                  // 50000 = 6250*8 exact
    float acc0 = 0.f, acc1 = 0.f, acc2 = 0.f;
    for (int k = 0; k < HID; ++k) {
        float cv = combined[(size_t)row * HID + k];
        acc0 += cv * Ws[0][k][col];
        acc1 += cv * Ws[1][k][col];
        acc2 += cv * Ws[2][k][col];
    }
    h2[(size_t)0 * NN * OUTF + (size_t)row * OUTF + col] = __float2half(acc0);
    h2[(size_t)1 * NN * OUTF + (size_t)row * OUTF + col] = __float2half(acc1);
    h2[(size_t)2 * NN * OUTF + (size_t)row * OUTF + col] = __float2half(acc2);
}

// ---------------- layer-2 aggregation: one wave per node, all 3 branches ----------------
__global__ __launch_bounds__(256) void k_agg2(
        const u64* __restrict__ csr, const int* __restrict__ cur, const int* __restrict__ cnt,
        const float* __restrict__ dinv,
        const float* __restrict__ b11, const float* __restrict__ b22, const float* __restrict__ b33,
        const __half* __restrict__ h2, float* __restrict__ out) {
    int f    = threadIdx.x & 31;
    int half = (threadIdx.x >> 5) & 1;
    int sub  = __builtin_amdgcn_readfirstlane(threadIdx.x >> 6);
    int n    = blockIdx.x * 4 + sub;

    float tot = b11[f] + b22[f] + b33[f];
#pragma unroll
    for (int b = 0; b < 3; ++b) {
        int i  = b * NN + n;
        int cc = cnt[i];
        int st = cur[i] - cc;
        const __half* h2b = h2 + (size_t)b * NN * OUTF;
        float accb = 0.f;
        for (int j = half; j < cc; j += 2) {
            u64 e0 = csr[st + j];
            int   s = (int)(unsigned int)(e0 & 0xffffffffULL);
            float w = __uint_as_float((unsigned int)(e0 >> 32));
            accb = fmaf(w, __half2float(h2b[(size_t)s * OUTF + f]), accb);
        }
        accb += __shfl_xor(accb, 32);
        float d = dinv[i];
        tot += accb + d * d * __half2float(h2b[(size_t)n * OUTF + f]);
    }
    if (half == 0) out[(size_t)n * OUTF + f] = tot;
}

// ---------------- launch ----------------
extern "C" void kernel_launch(void* const* d_in, const int* in_sizes, int n_in,
                              void* d_out, int out_size, void* d_ws, size_t ws_size,
                              hipStream_t stream) {
    const float* x1  = (const float*)d_in[0];
    const float* x2  = (const float*)d_in[1];
    const float* x3  = (const float*)d_in[2];
    const int*   ei1 = (const int*)d_in[3];
    const int*   ei2 = (const int*)d_in[4];
    const int*   ei3 = (const int*)d_in[5];
    const float* ew1 = (const float*)d_in[6];
    const float* ew2 = (const float*)d_in[7];
    const float* ew3 = (const float*)d_in[8];
    const float* W1  = (const float*)d_in[9];
    const float* W2  = (const float*)d_in[10];
    const float* W3  = (const float*)d_in[11];
    const float* b1  = (const float*)d_in[12];
    const float* b2  = (const float*)d_in[13];
    const float* b3  = (const float*)d_in[14];
    const float* fcw = (const float*)d_in[15];
    const float* fcb = (const float*)d_in[16];
    const float* W11 = (const float*)d_in[17];
    const float* W22 = (const float*)d_in[18];
    const float* W33 = (const float*)d_in[19];
    const float* b11 = (const float*)d_in[20];
    const float* b22 = (const float*)d_in[21];
    const float* b33 = (const float*)d_in[22];

    float* out = (float*)d_out;
    float* coef_out = out + (size_t)NN * OUTF;

    // workspace (8B-aligned items first)
    u64*   packed  = (u64*)d_ws;                           // 3N u64
    u64*   csr     = packed + TOTN;                        // 3E u64
    float* dinv    = (float*)(csr + 3 * EE);               // 3N
    int*   cnt     = (int*)(dinv + TOTN);                  // 3N
    int*   cur     = cnt + TOTN;                           // 3N
    int*   total   = cur + TOTN;                           // 64 pad
    __half* h      = (__half*)(total + 64);                // 3N*64 fp16
    float* comb    = (float*)(h + (size_t)TOTN * HID);     // N*64 fp32
    __half* h2     = (__half*)(comb + (size_t)NN * HID);   // 3N*32 fp16

    k_init<<<dim3((TOTN + 255) / 256), 256, 0, stream>>>(packed, total);
    k_hist<<<dim3(EE / 256, 3), 256, 0, stream>>>(ei1, ei2, ei3, ew1, ew2, ew3, packed);
    k_unpack<<<dim3((TOTN + 255) / 256), 256, 0, stream>>>(packed, dinv, cnt);
    k_offsets<<<dim3((TOTN + 1023) / 1024), 256, 0, stream>>>(cnt, cur, total);
    k_fill<<<dim3(EE / 256, 3), 256, 0, stream>>>(ei1, ei2, ei3, ew1, ew2, ew3,
                                                  dinv, cur, csr);

    k_gemm1<<<dim3((NN + BM - 1) / BM, 3), 256, 0, stream>>>(x1, x2, x3, W1, W2, W3, h);
    k_agg_attn<<<dim3(NN / 4), 256, 0, stream>>>(csr, cur, cnt, dinv, b1, b2, b3,
                                                 h, fcw, fcb, comb, coef_out);
    k_gemm2<<<dim3(NN / 8), 256, 0, stream>>>(comb, W11, W22, W33, h2);
    k_agg2<<<dim3(NN / 4), 256, 0, stream>>>(csr, cur, cnt, dinv,
                                             b11, b22, b33, h2, out);
}

// Round 5
// 398.893 us; speedup vs baseline: 2.9065x; 1.3933x over previous
//
#include <hip/hip_runtime.h>
#include <hip/hip_fp16.h>
#include <math.h>

#define NN   50000
#define INF_ 256
#define HID  64
#define OUTF 32
#define EE   800000
#define TOTN (3 * NN)
#define GB   782          // gemm blocks per branch: ceil(50000/64)
#define HB   3125         // hist blocks per branch: 800000/256
#define MASK40 ((1ULL << 40) - 1)

typedef unsigned long long u64;
typedef unsigned int       u32;
typedef unsigned short     u16;

// ---------------- init: packed hist = 0, total = 0 ----------------
__global__ __launch_bounds__(256) void k_init(u64* __restrict__ packed, int* __restrict__ total) {
    int i = blockIdx.x * 256 + threadIdx.x;
    if (i < TOTN) packed[i] = 0ULL;
    if (i == 0) *total = 0;
}

// ---------------- fused: histogram (atomic, returns rank) + layer-1 GEMM ----------------
// blockIdx.x < GB: gemm tile (64 rows x 64 cols, BK=32).  >= GB: 256-edge hist chunk.
__global__ __launch_bounds__(256) void k_histgemm(
        const int* __restrict__ ei1, const int* __restrict__ ei2, const int* __restrict__ ei3,
        const float* __restrict__ ew1, const float* __restrict__ ew2, const float* __restrict__ ew3,
        u64* __restrict__ packed, u16* __restrict__ rank,
        const float* __restrict__ x1, const float* __restrict__ x2, const float* __restrict__ x3,
        const float* __restrict__ W1, const float* __restrict__ W2, const float* __restrict__ W3,
        __half* __restrict__ h) {
    __shared__ float xs[64][36];    // 9.2 KB
    __shared__ float Ws[32][68];    // 8.7 KB  -> 17.9 KB total, 8 blocks/CU
    int b = blockIdx.y;

    if (blockIdx.x >= GB) {         // ---- hist part ----
        const int*   ei = (b == 0) ? ei1 : (b == 1) ? ei2 : ei3;
        const float* ew = (b == 0) ? ew1 : (b == 1) ? ew2 : ew3;
        int e = (blockIdx.x - GB) * 256 + threadIdx.x;   // HB*256 == EE exact
        int dst = ei[EE + e];
        u64 contrib = (1ULL << 40) | (u64)(u32)(ew[e] * 16777216.0f);
        u64 old = atomicAdd(&packed[b * NN + dst], contrib);
        rank[(size_t)b * EE + e] = (u16)(old >> 40);
        return;
    }

    // ---- gemm part: h = x @ W (fp16 out) ----
    const float* x = (b == 0) ? x1 : (b == 1) ? x2 : x3;
    const float* W = (b == 0) ? W1 : (b == 1) ? W2 : W3;
    __half* hb = h + (size_t)b * NN * HID;

    int t  = threadIdx.x;
    int tx = t & 15;
    int ty = t >> 4;
    int row_base = blockIdx.x * 64;

    float acc[4][4] = {};
    const float4* x4 = reinterpret_cast<const float4*>(x);
    const float4* W4 = reinterpret_cast<const float4*>(W);
    for (int kt = 0; kt < INF_ / 32; ++kt) {
#pragma unroll
        for (int j = 0; j < 2; ++j) {               // stage x: 512 float4
            int flat = t + j * 256;
            int r = flat >> 3, c4 = flat & 7;
            int gr = row_base + r;
            float4 v = (gr < NN)
                ? x4[(size_t)gr * (INF_ / 4) + kt * 8 + c4]
                : make_float4(0.f, 0.f, 0.f, 0.f);
            *reinterpret_cast<float4*>(&xs[r][c4 * 4]) = v;
        }
#pragma unroll
        for (int j = 0; j < 2; ++j) {               // stage W: 512 float4
            int flat = t + j * 256;
            int r = flat >> 4, c4 = flat & 15;
            *reinterpret_cast<float4*>(&Ws[r][c4 * 4]) = W4[(kt * 32 + r) * 16 + c4];
        }
        __syncthreads();
#pragma unroll
        for (int k = 0; k < 32; ++k) {
            float4 wv = *reinterpret_cast<const float4*>(&Ws[k][tx * 4]);
            float xv[4];
#pragma unroll
            for (int i = 0; i < 4; ++i) xv[i] = xs[ty * 4 + i][k];
#pragma unroll
            for (int i = 0; i < 4; ++i) {
                acc[i][0] = fmaf(xv[i], wv.x, acc[i][0]);
                acc[i][1] = fmaf(xv[i], wv.y, acc[i][1]);
                acc[i][2] = fmaf(xv[i], wv.z, acc[i][2]);
                acc[i][3] = fmaf(xv[i], wv.w, acc[i][3]);
            }
        }
        __syncthreads();
    }
#pragma unroll
    for (int i = 0; i < 4; ++i) {
        int row = row_base + ty * 4 + i;
        if (row < NN) {
            ushort4 v;
            v.x = __half_as_ushort(__float2half(acc[i][0]));
            v.y = __half_as_ushort(__float2half(acc[i][1]));
            v.z = __half_as_ushort(__float2half(acc[i][2]));
            v.w = __half_as_ushort(__float2half(acc[i][3]));
            *reinterpret_cast<ushort4*>(&hb[(size_t)row * HID + tx * 4]) = v;
        }
    }
}

// ---------------- offsets: unpack packed -> cnt/dinv, block scan -> start ----------------
__global__ __launch_bounds__(256) void k_offsets(const u64* __restrict__ packed,
                                                 int* __restrict__ cnt, float* __restrict__ dinv,
                                                 int* __restrict__ start, int* __restrict__ total) {
    __shared__ int s[256];
    __shared__ int s_base;
    int t = threadIdx.x;
    int base_i = blockIdx.x * 1024 + t * 4;
    int c[4]; int sum = 0;
#pragma unroll
    for (int k = 0; k < 4; ++k) {
        int i = base_i + k;
        if (i < TOTN) {
            u64 p = packed[i];
            c[k] = (int)(p >> 40);
            cnt[i] = c[k];
            dinv[i] = rsqrtf(1.0f + (float)(p & MASK40) * (1.0f / 16777216.0f));
        } else c[k] = 0;
        sum += c[k];
    }
    s[t] = sum;
    __syncthreads();
    for (int d = 1; d < 256; d <<= 1) {
        int v = (t >= d) ? s[t - d] : 0;
        __syncthreads();
        s[t] += v;
        __syncthreads();
    }
    if (t == 255) s_base = atomicAdd(total, s[255]);
    __syncthreads();
    int run = s_base + s[t] - sum;
#pragma unroll
    for (int k = 0; k < 4; ++k) {
        int i = base_i + k;
        if (i < TOTN) start[i] = run;
        run += c[k];
    }
}

// ---------------- fill CSR (atomic-free): csr[start+rank] = fp16(norm)<<16 | src ----------------
__global__ __launch_bounds__(256) void k_fill(
        const int* __restrict__ ei1, const int* __restrict__ ei2, const int* __restrict__ ei3,
        const float* __restrict__ ew1, const float* __restrict__ ew2, const float* __restrict__ ew3,
        const float* __restrict__ dinv, const int* __restrict__ start,
        const u16* __restrict__ rank, u32* __restrict__ csr) {
    int b = blockIdx.y;
    const int*   ei = (b == 0) ? ei1 : (b == 1) ? ei2 : ei3;
    const float* ew = (b == 0) ? ew1 : (b == 1) ? ew2 : ew3;
    int e = blockIdx.x * 256 + threadIdx.x;
    int src = ei[e];
    int dst = ei[EE + e];
    float norm = dinv[b * NN + src] * ew[e] * dinv[b * NN + dst];
    int pos = start[b * NN + dst] + (int)rank[(size_t)b * EE + e];
    csr[pos] = ((u32)__half_as_ushort(__float2half(norm)) << 16) | (u32)src;
}

// ---------------- fused layer-1 aggregation (3 branches) + attention ----------------
__global__ __launch_bounds__(256) void k_agg_attn(
        const u32* __restrict__ csr, const int* __restrict__ start, const int* __restrict__ cnt,
        const float* __restrict__ dinv,
        const float* __restrict__ b1, const float* __restrict__ b2, const float* __restrict__ b3,
        const __half* __restrict__ h,
        const float* __restrict__ fc_w, const float* __restrict__ fc_b,
        float* __restrict__ combined, float* __restrict__ coef_out) {
    int f   = threadIdx.x & 63;
    int sub = __builtin_amdgcn_readfirstlane(threadIdx.x >> 6);
    int n   = blockIdx.x * 4 + sub;                  // 50000 = 12500*4 exact
    float wv = fc_w[f];
    float fb = fc_b[0];

    float ev[3], c[3];
#pragma unroll
    for (int b = 0; b < 3; ++b) {
        const float* bi = (b == 0) ? b1 : (b == 1) ? b2 : b3;
        const __half* hb = h + (size_t)b * NN * HID;
        int i  = b * NN + n;
        int cc = cnt[i];
        int st = start[i];
        float d = dinv[i];
        float acc = bi[f] + d * d * __half2float(hb[(size_t)n * HID + f]);

        int j = 0;
        for (; j + 4 <= cc; j += 4) {
            u32 e0 = csr[st + j],     e1 = csr[st + j + 1];
            u32 e2 = csr[st + j + 2], e3 = csr[st + j + 3];
            float v0 = __half2float(hb[(size_t)(e0 & 0xffff) * HID + f]);
            float v1 = __half2float(hb[(size_t)(e1 & 0xffff) * HID + f]);
            float v2 = __half2float(hb[(size_t)(e2 & 0xffff) * HID + f]);
            float v3 = __half2float(hb[(size_t)(e3 & 0xffff) * HID + f]);
            acc = fmaf(__half2float(__ushort_as_half((u16)(e0 >> 16))), v0, acc);
            acc = fmaf(__half2float(__ushort_as_half((u16)(e1 >> 16))), v1, acc);
            acc = fmaf(__half2float(__ushort_as_half((u16)(e2 >> 16))), v2, acc);
            acc = fmaf(__half2float(__ushort_as_half((u16)(e3 >> 16))), v3, acc);
        }
        for (; j < cc; ++j) {
            u32 e0 = csr[st + j];
            acc = fmaf(__half2float(__ushort_as_half((u16)(e0 >> 16))),
                       __half2float(hb[(size_t)(e0 & 0xffff) * HID + f]), acc);
        }
        ev[b] = fmaxf(acc, 0.f);                     // ReLU

        float dd = ev[b] * wv;
#pragma unroll
        for (int off = 32; off > 0; off >>= 1) dd += __shfl_xor(dd, off);
        float z = dd + fb;
        z = (z > 0.f) ? z : 0.01f * z;
        c[b] = expf(z);
    }
    float cd = c[0] + c[1] + c[2];
    float coef0 = c[0] / cd, coef1 = c[1] / cd, coef2 = c[2] / cd;
    combined[(size_t)n * HID + f] = ev[0] * coef0 + ev[1] * coef1 + ev[2] * coef2;
    if (f == 0) {
        coef_out[n]          = coef0;
        coef_out[NN + n]     = coef1;
        coef_out[2 * NN + n] = coef2;
    }
}

// ---------------- layer-2 GEMM: h2[b] = combined @ W_b (fp16 out) ----------------
__global__ __launch_bounds__(256) void k_gemm2(
        const float* __restrict__ combined,
        const float* __restrict__ W11, const float* __restrict__ W22, const float* __restrict__ W33,
        __half* __restrict__ h2) {
    __shared__ float Ws[3][HID][OUTF];
    int t = threadIdx.x;
    for (int idx = t; idx < HID * OUTF; idx += 256) {
        Ws[0][idx >> 5][idx & 31] = W11[idx];
        Ws[1][idx >> 5][idx & 31] = W22[idx];
        Ws[2][idx >> 5][idx & 31] = W33[idx];
    }
    __syncthreads();

    int col = t & 31;
    int sub = t >> 5;
    int row = blockIdx.x * 8 + sub;                  // 50000 = 6250*8 exact
    float acc0 = 0.f, acc1 = 0.f, acc2 = 0.f;
    for (int k = 0; k < HID; ++k) {
        float cv = combined[(size_t)row * HID + k];
        acc0 += cv * Ws[0][k][col];
        acc1 += cv * Ws[1][k][col];
        acc2 += cv * Ws[2][k][col];
    }
    h2[(size_t)0 * NN * OUTF + (size_t)row * OUTF + col] = __float2half(acc0);
    h2[(size_t)1 * NN * OUTF + (size_t)row * OUTF + col] = __float2half(acc1);
    h2[(size_t)2 * NN * OUTF + (size_t)row * OUTF + col] = __float2half(acc2);
}

// ---------------- layer-2 aggregation: one wave per node, all 3 branches ----------------
__global__ __launch_bounds__(256) void k_agg2(
        const u32* __restrict__ csr, const int* __restrict__ start, const int* __restrict__ cnt,
        const float* __restrict__ dinv,
        const float* __restrict__ b11, const float* __restrict__ b22, const float* __restrict__ b33,
        const __half* __restrict__ h2, float* __restrict__ out) {
    int f    = threadIdx.x & 31;
    int half = (threadIdx.x >> 5) & 1;
    int sub  = __builtin_amdgcn_readfirstlane(threadIdx.x >> 6);
    int n    = blockIdx.x * 4 + sub;

    float tot = b11[f] + b22[f] + b33[f];
#pragma unroll
    for (int b = 0; b < 3; ++b) {
        int i  = b * NN + n;
        int cc = cnt[i];
        int st = start[i];
        const __half* h2b = h2 + (size_t)b * NN * OUTF;
        float accb = 0.f;
        for (int j = half; j < cc; j += 2) {
            u32 e0 = csr[st + j];
            accb = fmaf(__half2float(__ushort_as_half((u16)(e0 >> 16))),
                        __half2float(h2b[(size_t)(e0 & 0xffff) * OUTF + f]), accb);
        }
        accb += __shfl_xor(accb, 32);
        float d = dinv[i];
        tot += accb + d * d * __half2float(h2b[(size_t)n * OUTF + f]);
    }
    if (half == 0) out[(size_t)n * OUTF + f] = tot;
}

// ---------------- launch ----------------
extern "C" void kernel_launch(void* const* d_in, const int* in_sizes, int n_in,
                              void* d_out, int out_size, void* d_ws, size_t ws_size,
                              hipStream_t stream) {
    const float* x1  = (const float*)d_in[0];
    const float* x2  = (const float*)d_in[1];
    const float* x3  = (const float*)d_in[2];
    const int*   ei1 = (const int*)d_in[3];
    const int*   ei2 = (const int*)d_in[4];
    const int*   ei3 = (const int*)d_in[5];
    const float* ew1 = (const float*)d_in[6];
    const float* ew2 = (const float*)d_in[7];
    const float* ew3 = (const float*)d_in[8];
    const float* W1  = (const float*)d_in[9];
    const float* W2  = (const float*)d_in[10];
    const float* W3  = (const float*)d_in[11];
    const float* b1  = (const float*)d_in[12];
    const float* b2  = (const float*)d_in[13];
    const float* b3  = (const float*)d_in[14];
    const float* fcw = (const float*)d_in[15];
    const float* fcb = (const float*)d_in[16];
    const float* W11 = (const float*)d_in[17];
    const float* W22 = (const float*)d_in[18];
    const float* W33 = (const float*)d_in[19];
    const float* b11 = (const float*)d_in[20];
    const float* b22 = (const float*)d_in[21];
    const float* b33 = (const float*)d_in[22];

    float* out = (float*)d_out;
    float* coef_out = out + (size_t)NN * OUTF;

    // workspace layout (descending alignment)
    u64*   packed = (u64*)d_ws;                            // 3N u64      1.2 MB
    u32*   csr    = (u32*)(packed + TOTN);                 // 3E u32      9.6 MB
    u16*   rank   = (u16*)(csr + 3 * EE);                  // 3E u16      4.8 MB
    float* dinv   = (float*)(rank + 3 * EE);               // 3N f32
    int*   cnt    = (int*)(dinv + TOTN);                   // 3N
    int*   start  = cnt + TOTN;                            // 3N
    int*   total  = start + TOTN;                          // 64 pad
    __half* h     = (__half*)(total + 64);                 // 3N*64 fp16  19.2 MB
    float* comb   = (float*)(h + (size_t)TOTN * HID);      // N*64 fp32   12.8 MB
    __half* h2    = (__half*)(comb + (size_t)NN * HID);    // 3N*32 fp16   9.6 MB

    k_init<<<dim3((TOTN + 255) / 256), 256, 0, stream>>>(packed, total);
    k_histgemm<<<dim3(GB + HB, 3), 256, 0, stream>>>(ei1, ei2, ei3, ew1, ew2, ew3,
                                                     packed, rank,
                                                     x1, x2, x3, W1, W2, W3, h);
    k_offsets<<<dim3((TOTN + 1023) / 1024), 256, 0, stream>>>(packed, cnt, dinv, start, total);
    k_fill<<<dim3(EE / 256, 3), 256, 0, stream>>>(ei1, ei2, ei3, ew1, ew2, ew3,
                                                  dinv, start, rank, csr);

    k_agg_attn<<<dim3(NN / 4), 256, 0, stream>>>(csr, start, cnt, dinv, b1, b2, b3,
                                                 h, fcw, fcb, comb, coef_out);
    k_gemm2<<<dim3(NN / 8), 256, 0, stream>>>(comb, W11, W22, W33, h2);
    k_agg2<<<dim3(NN / 4), 256, 0, stream>>>(csr, start, cnt, dinv,
                                             b11, b22, b33, h2, out);
}